// Round 2
// baseline (102.739 us; speedup 1.0000x reference)
//
#include <hip/hip_runtime.h>

#define GRAV_EPS 0.01f

// ---- Pre-pass: repack x [N][129] -> pos [N][128] (512B-aligned rows) + mass [N]
__global__ __launch_bounds__(128) void grav_repack_kernel(
    const float* __restrict__ x,
    float*       __restrict__ pos,
    float*       __restrict__ mass,
    int N)
{
    int n = blockIdx.x;
    if (n >= N) return;
    int t = threadIdx.x;                   // 0..127
    const float* row = x + (long)n * 129;
    pos[(long)n * 128 + t] = row[t];
    if (t == 0) mass[n] = row[128];
}

// ---- Main: 32 lanes per edge, one float4 per lane = whole 512B row per instr
__global__ __launch_bounds__(256) void DecoderGravity_33268816675213_kernel(
    const float* __restrict__ pos,
    const float* __restrict__ mass,
    const int*   __restrict__ eli,
    const float* __restrict__ lp,
    float*       __restrict__ out,
    int E)
{
    int tid  = blockIdx.x * blockDim.x + threadIdx.x;
    int edge = tid >> 5;
    int lane = tid & 31;
    if (edge >= E) return;

    int s = eli[edge];
    int d = eli[E + edge];

    const float4* __restrict__ ps = (const float4*)(pos + (long)s * 128);
    const float4* __restrict__ pd = (const float4*)(pos + (long)d * 128);

    float4 a = ps[lane];
    float4 b = pd[lane];

    float dx = a.x - b.x;
    float dy = a.y - b.y;
    float dz = a.z - b.z;
    float dw = a.w - b.w;
    float sum = dx * dx;
    sum = fmaf(dy, dy, sum);
    sum = fmaf(dz, dz, sum);
    sum = fmaf(dw, dw, sum);

    // Butterfly reduce across the 32-lane group
    sum += __shfl_xor(sum, 1);
    sum += __shfl_xor(sum, 2);
    sum += __shfl_xor(sum, 4);
    sum += __shfl_xor(sum, 8);
    sum += __shfl_xor(sum, 16);

    if (lane == 0) {
        float m = mass[d];                 // L2-resident (200 KB)
        out[edge] = m - lp[0] * logf(sum + GRAV_EPS);
    }
}

// ---- Fallback (R1 kernel) if ws too small
__global__ __launch_bounds__(256) void grav_fallback_kernel(
    const float* __restrict__ x,
    const int*   __restrict__ eli,
    const float* __restrict__ lp,
    float*       __restrict__ out,
    int E)
{
    const int STRIDE = 129;
    int tid  = blockIdx.x * blockDim.x + threadIdx.x;
    int edge = tid >> 5;
    int lane = tid & 31;
    if (edge >= E) return;

    int s = eli[edge];
    int d = eli[E + edge];
    const float* xs = x + (long)s * STRIDE;
    const float* xd = x + (long)d * STRIDE;

    float sum = 0.0f;
    #pragma unroll
    for (int k = 0; k < 4; ++k) {
        float df = xs[lane + 32 * k] - xd[lane + 32 * k];
        sum = fmaf(df, df, sum);
    }
    sum += __shfl_xor(sum, 1);
    sum += __shfl_xor(sum, 2);
    sum += __shfl_xor(sum, 4);
    sum += __shfl_xor(sum, 8);
    sum += __shfl_xor(sum, 16);

    if (lane == 0) out[edge] = xd[128] - lp[0] * logf(sum + GRAV_EPS);
}

extern "C" void kernel_launch(void* const* d_in, const int* in_sizes, int n_in,
                              void* d_out, int out_size, void* d_ws, size_t ws_size,
                              hipStream_t stream) {
    const float* x   = (const float*)d_in[0];
    const int*   eli = (const int*)d_in[1];
    const float* lp  = (const float*)d_in[2];
    float*       out = (float*)d_out;

    int N = in_sizes[0] / 129;
    int E = in_sizes[1] / 2;

    size_t pos_bytes  = (size_t)N * 128 * sizeof(float);
    size_t mass_bytes = (size_t)N * sizeof(float);

    int threads = 256;
    long total  = (long)E * 32;
    int blocks  = (int)((total + threads - 1) / threads);

    if (ws_size >= pos_bytes + mass_bytes) {
        float* pos  = (float*)d_ws;
        float* mass = (float*)((char*)d_ws + pos_bytes);

        grav_repack_kernel<<<N, 128, 0, stream>>>(x, pos, mass, N);
        DecoderGravity_33268816675213_kernel<<<blocks, threads, 0, stream>>>(
            pos, mass, eli, lp, out, E);
    } else {
        grav_fallback_kernel<<<blocks, threads, 0, stream>>>(x, eli, lp, out, E);
    }
}

// Round 3
// 54.360 us; speedup vs baseline: 1.8900x; 1.8900x over previous
//
#include <hip/hip_runtime.h>
#include <hip/hip_bf16.h>

#define GRAV_EPS 0.01f

__device__ inline float blo(unsigned int w) { return __uint_as_float(w << 16); }
__device__ inline float bhi(unsigned int w) { return __uint_as_float(w & 0xFFFF0000u); }

// ---- Pre-pass: x[N][129] f32 -> posb[N][128] bf16 (256B rows) + mass[N] f32
__global__ __launch_bounds__(256) void grav_repack_bf16(
    const float* __restrict__ x,
    unsigned int* __restrict__ posb,   // N*64 words, 2 bf16 each
    float*        __restrict__ mass,
    int N)
{
    int row = blockIdx.x * 4 + (threadIdx.x >> 6);
    int c   = threadIdx.x & 63;                  // pair index 0..63
    if (row >= N) return;
    const float* src = x + (long)row * 129;
    float f0 = src[2 * c];
    float f1 = src[2 * c + 1];
    __hip_bfloat162 h2(__float2bfloat16(f0), __float2bfloat16(f1));
    posb[(long)row * 64 + c] = *reinterpret_cast<unsigned int*>(&h2);
    if (c == 0) mass[row] = src[128];
}

// ---- Main: 16 lanes per edge, one uint4 (8 bf16) per lane = whole 256B row
__global__ __launch_bounds__(256) void DecoderGravity_33268816675213_kernel(
    const unsigned int* __restrict__ posb,
    const float*        __restrict__ mass,
    const int*          __restrict__ eli,
    const float*        __restrict__ lp,
    float*              __restrict__ out,
    int E)
{
    int tid  = blockIdx.x * blockDim.x + threadIdx.x;
    int edge = tid >> 4;
    int lane = tid & 15;
    if (edge >= E) return;

    int s = eli[edge];
    int d = eli[E + edge];

    const uint4* __restrict__ ps = (const uint4*)(posb + (long)s * 64);
    const uint4* __restrict__ pd = (const uint4*)(posb + (long)d * 64);

    uint4 a = ps[lane];
    uint4 b = pd[lane];

    float sum = 0.0f;
    {
        float d0 = blo(a.x) - blo(b.x);
        float d1 = bhi(a.x) - bhi(b.x);
        float d2 = blo(a.y) - blo(b.y);
        float d3 = bhi(a.y) - bhi(b.y);
        float d4 = blo(a.z) - blo(b.z);
        float d5 = bhi(a.z) - bhi(b.z);
        float d6 = blo(a.w) - blo(b.w);
        float d7 = bhi(a.w) - bhi(b.w);
        sum = d0 * d0;
        sum = fmaf(d1, d1, sum);
        sum = fmaf(d2, d2, sum);
        sum = fmaf(d3, d3, sum);
        sum = fmaf(d4, d4, sum);
        sum = fmaf(d5, d5, sum);
        sum = fmaf(d6, d6, sum);
        sum = fmaf(d7, d7, sum);
    }

    // Butterfly reduce across the 16-lane group (masks stay inside the group)
    sum += __shfl_xor(sum, 1);
    sum += __shfl_xor(sum, 2);
    sum += __shfl_xor(sum, 4);
    sum += __shfl_xor(sum, 8);

    if (lane == 0) {
        out[edge] = mass[d] - lp[0] * logf(sum + GRAV_EPS);
    }
}

// ---- Fallback (no-workspace path)
__global__ __launch_bounds__(256) void grav_fallback_kernel(
    const float* __restrict__ x,
    const int*   __restrict__ eli,
    const float* __restrict__ lp,
    float*       __restrict__ out,
    int E)
{
    const int STRIDE = 129;
    int tid  = blockIdx.x * blockDim.x + threadIdx.x;
    int edge = tid >> 5;
    int lane = tid & 31;
    if (edge >= E) return;

    int s = eli[edge];
    int d = eli[E + edge];
    const float* xs = x + (long)s * STRIDE;
    const float* xd = x + (long)d * STRIDE;

    float sum = 0.0f;
    #pragma unroll
    for (int k = 0; k < 4; ++k) {
        float df = xs[lane + 32 * k] - xd[lane + 32 * k];
        sum = fmaf(df, df, sum);
    }
    sum += __shfl_xor(sum, 1);
    sum += __shfl_xor(sum, 2);
    sum += __shfl_xor(sum, 4);
    sum += __shfl_xor(sum, 8);
    sum += __shfl_xor(sum, 16);

    if (lane == 0) out[edge] = xd[128] - lp[0] * logf(sum + GRAV_EPS);
}

extern "C" void kernel_launch(void* const* d_in, const int* in_sizes, int n_in,
                              void* d_out, int out_size, void* d_ws, size_t ws_size,
                              hipStream_t stream) {
    const float* x   = (const float*)d_in[0];
    const int*   eli = (const int*)d_in[1];
    const float* lp  = (const float*)d_in[2];
    float*       out = (float*)d_out;

    int N = in_sizes[0] / 129;
    int E = in_sizes[1] / 2;

    size_t posb_bytes = (size_t)N * 128 * sizeof(unsigned short); // bf16
    size_t mass_bytes = (size_t)N * sizeof(float);

    if (ws_size >= posb_bytes + mass_bytes) {
        unsigned int* posb = (unsigned int*)d_ws;
        float*        mass = (float*)((char*)d_ws + posb_bytes);

        int rblocks = (N + 3) / 4;
        grav_repack_bf16<<<rblocks, 256, 0, stream>>>(x, posb, mass, N);

        long total  = (long)E * 16;
        int blocks  = (int)((total + 255) / 256);
        DecoderGravity_33268816675213_kernel<<<blocks, 256, 0, stream>>>(
            posb, mass, eli, lp, out, E);
    } else {
        long total  = (long)E * 32;
        int blocks  = (int)((total + 255) / 256);
        grav_fallback_kernel<<<blocks, 256, 0, stream>>>(x, eli, lp, out, E);
    }
}

// Round 4
// 32.743 us; speedup vs baseline: 3.1377x; 1.6602x over previous
//
#include <hip/hip_runtime.h>

#define GRAV_EPS 0.01f

typedef float v2f __attribute__((ext_vector_type(2)));

// ---- Pre-pass: x[N][129] f32 -> posf8[N][128] fp8 e4m3 (128B rows) + mass[N] f32
// One thread packs one 32-bit word (4 elements).
__global__ __launch_bounds__(256) void grav_repack_fp8(
    const float*  __restrict__ x,
    unsigned int* __restrict__ posf8,   // N*32 words
    float*        __restrict__ mass,
    long total_words, int N)
{
    long w = (long)blockIdx.x * blockDim.x + threadIdx.x;
    if (w >= total_words) return;
    int row = (int)(w >> 5);
    int c   = (int)(w & 31);
    const float* src = x + (long)row * 129 + c * 4;
    float f0 = src[0], f1 = src[1], f2 = src[2], f3 = src[3];
    int word = 0;
    word = __builtin_amdgcn_cvt_pk_fp8_f32(f0, f1, word, false);
    word = __builtin_amdgcn_cvt_pk_fp8_f32(f2, f3, word, true);
    posf8[w] = (unsigned int)word;
    if (c == 0) mass[row] = x[(long)row * 129 + 128];
}

// ---- Main: 8 lanes per edge, one uint4 (16 fp8) per lane = whole 128B row
__global__ __launch_bounds__(256) void DecoderGravity_33268816675213_kernel(
    const uint4* __restrict__ posf8,    // N rows x 8 uint4
    const float* __restrict__ mass,
    const int*   __restrict__ eli,
    const float* __restrict__ lp,
    float*       __restrict__ out,
    int E)
{
    int tid  = blockIdx.x * blockDim.x + threadIdx.x;
    int edge = tid >> 3;
    int lane = tid & 7;
    if (edge >= E) return;

    int s = eli[edge];
    int d = eli[E + edge];

    uint4 a = posf8[(long)s * 8 + lane];
    uint4 b = posf8[(long)d * 8 + lane];

    v2f acc = {0.0f, 0.0f};
    {
        v2f a0, a1, b0, b1, d0, d1;
        // word x
        a0 = __builtin_amdgcn_cvt_pk_f32_fp8((int)a.x, false);
        a1 = __builtin_amdgcn_cvt_pk_f32_fp8((int)a.x, true);
        b0 = __builtin_amdgcn_cvt_pk_f32_fp8((int)b.x, false);
        b1 = __builtin_amdgcn_cvt_pk_f32_fp8((int)b.x, true);
        d0 = a0 - b0; d1 = a1 - b1;
        acc += d0 * d0; acc += d1 * d1;
        // word y
        a0 = __builtin_amdgcn_cvt_pk_f32_fp8((int)a.y, false);
        a1 = __builtin_amdgcn_cvt_pk_f32_fp8((int)a.y, true);
        b0 = __builtin_amdgcn_cvt_pk_f32_fp8((int)b.y, false);
        b1 = __builtin_amdgcn_cvt_pk_f32_fp8((int)b.y, true);
        d0 = a0 - b0; d1 = a1 - b1;
        acc += d0 * d0; acc += d1 * d1;
        // word z
        a0 = __builtin_amdgcn_cvt_pk_f32_fp8((int)a.z, false);
        a1 = __builtin_amdgcn_cvt_pk_f32_fp8((int)a.z, true);
        b0 = __builtin_amdgcn_cvt_pk_f32_fp8((int)b.z, false);
        b1 = __builtin_amdgcn_cvt_pk_f32_fp8((int)b.z, true);
        d0 = a0 - b0; d1 = a1 - b1;
        acc += d0 * d0; acc += d1 * d1;
        // word w
        a0 = __builtin_amdgcn_cvt_pk_f32_fp8((int)a.w, false);
        a1 = __builtin_amdgcn_cvt_pk_f32_fp8((int)a.w, true);
        b0 = __builtin_amdgcn_cvt_pk_f32_fp8((int)b.w, false);
        b1 = __builtin_amdgcn_cvt_pk_f32_fp8((int)b.w, true);
        d0 = a0 - b0; d1 = a1 - b1;
        acc += d0 * d0; acc += d1 * d1;
    }
    float sum = acc.x + acc.y;

    // Butterfly reduce across the 8-lane group
    sum += __shfl_xor(sum, 1);
    sum += __shfl_xor(sum, 2);
    sum += __shfl_xor(sum, 4);

    if (lane == 0) {
        out[edge] = mass[d] - lp[0] * logf(sum + GRAV_EPS);
    }
}

// ---- Fallback (no-workspace path): fp32 direct
__global__ __launch_bounds__(256) void grav_fallback_kernel(
    const float* __restrict__ x,
    const int*   __restrict__ eli,
    const float* __restrict__ lp,
    float*       __restrict__ out,
    int E)
{
    const int STRIDE = 129;
    int tid  = blockIdx.x * blockDim.x + threadIdx.x;
    int edge = tid >> 5;
    int lane = tid & 31;
    if (edge >= E) return;

    int s = eli[edge];
    int d = eli[E + edge];
    const float* xs = x + (long)s * STRIDE;
    const float* xd = x + (long)d * STRIDE;

    float sum = 0.0f;
    #pragma unroll
    for (int k = 0; k < 4; ++k) {
        float df = xs[lane + 32 * k] - xd[lane + 32 * k];
        sum = fmaf(df, df, sum);
    }
    sum += __shfl_xor(sum, 1);
    sum += __shfl_xor(sum, 2);
    sum += __shfl_xor(sum, 4);
    sum += __shfl_xor(sum, 8);
    sum += __shfl_xor(sum, 16);

    if (lane == 0) out[edge] = xd[128] - lp[0] * logf(sum + GRAV_EPS);
}

extern "C" void kernel_launch(void* const* d_in, const int* in_sizes, int n_in,
                              void* d_out, int out_size, void* d_ws, size_t ws_size,
                              hipStream_t stream) {
    const float* x   = (const float*)d_in[0];
    const int*   eli = (const int*)d_in[1];
    const float* lp  = (const float*)d_in[2];
    float*       out = (float*)d_out;

    int N = in_sizes[0] / 129;
    int E = in_sizes[1] / 2;

    size_t posf8_bytes = (size_t)N * 128;          // fp8: 128 B per row
    size_t mass_bytes  = (size_t)N * sizeof(float);

    if (ws_size >= posf8_bytes + mass_bytes) {
        unsigned int* posf8 = (unsigned int*)d_ws;
        float*        mass  = (float*)((char*)d_ws + posf8_bytes);

        long total_words = (long)N * 32;
        int rblocks = (int)((total_words + 255) / 256);
        grav_repack_fp8<<<rblocks, 256, 0, stream>>>(x, posf8, mass, total_words, N);

        long total = (long)E * 8;
        int blocks = (int)((total + 255) / 256);
        DecoderGravity_33268816675213_kernel<<<blocks, 256, 0, stream>>>(
            (const uint4*)posf8, mass, eli, lp, out, E);
    } else {
        long total = (long)E * 32;
        int blocks = (int)((total + 255) / 256);
        grav_fallback_kernel<<<blocks, 256, 0, stream>>>(x, eli, lp, out, E);
    }
}